// Round 3
// baseline (1050.297 us; speedup 1.0000x reference)
//
#include <hip/hip_runtime.h>
#include <hip/hip_bf16.h>

// MHRetention (B=4, L=4096, EMB=2048, H=16, hd=128), fp32 in/out, bf16 MFMA compute.
// Pipeline:
//  1) cvt x -> bf16; per-stage cvt w* -> bf16 (single reused buffer)
//  2) Q = relu(x wq^T)/sqrt(128)            -> Qb  [16384][2048]
//     K = relu(x wk^T)/sqrt(128), V = x wv^T -> KT,VT [bh][feat][l] (transposed, in d_out scratch)
//     U = silu(x wu^T)                       -> Ub  [16384][2048]
//  3) KVT[bh][e][d] = sum_l VT[e][l]*KT[d][l]  (4 L-chunks fp32 partials -> reduce -> bf16)
//  4) Oraw[l][h*128+e] = sum_d Q[l][d]*KVT[e][d]   (written into d_out's KT region, then dead)
//  5) Ob = Oraw / max(sqrt(ss/128),1e-12) * U      (Ob aliases xb)
//  6) out = Ob wo^T (fp32 -> d_out, full overwrite)
// ws high-water: 218 MiB.

typedef unsigned int u32;
typedef unsigned short u16;
typedef __bf16 bf16x8 __attribute__((ext_vector_type(8)));
typedef float f32x4 __attribute__((ext_vector_type(4)));

__device__ __forceinline__ u16 f2bf(float f) {
  u32 u = __float_as_uint(f);
  u = (u + 0x7fffu + ((u >> 16) & 1u)) >> 16;
  return (u16)u;
}
__device__ __forceinline__ float bf2f(u16 s) { return __uint_as_float(((u32)s) << 16); }

__device__ __forceinline__ void gl_lds16(const void* g, void* l) {
  __builtin_amdgcn_global_load_lds((const __attribute__((address_space(1))) void*)g,
                                   (__attribute__((address_space(3))) void*)l, 16, 0, 0);
}

#define INV_SCALE 0.08838834764831845f  // 1/sqrt(128)

// ---------------- fp32 -> bf16 conversion ----------------
__global__ __launch_bounds__(256) void cvt_f32_bf16(const float4* __restrict__ in,
                                                    u16* __restrict__ out, int n4) {
  int i = blockIdx.x * 256 + threadIdx.x;
  int stride = gridDim.x * 256;
  for (; i < n4; i += stride) {
    float4 v = in[i];
    u32 lo = (u32)f2bf(v.x) | ((u32)f2bf(v.y) << 16);
    u32 hi = (u32)f2bf(v.z) | ((u32)f2bf(v.w) << 16);
    ((uint2*)out)[i] = make_uint2(lo, hi);
  }
}

// ---------------- generic 128x128-tile bf16 gemm_bt ----------------
// C[m][n] = sum_k A[m][k] * B[n][k]   (both operands K-contiguous)
// MODE: 0=Q(relu/scale), 1=K(relu/scale, transposed KT), 2=V(transposed VT),
//       3=U(silu), 4=KV partial (fp32), 5=O (bf16), 6=final (fp32)
template <int MODE>
__global__ __launch_bounds__(256) void gemm128(const u16* __restrict__ Ab,
                                               const u16* __restrict__ Bb,
                                               void* __restrict__ Cb) {
  constexpr int ldA = (MODE == 4) ? 4096 : 2048;
  constexpr int ldB = (MODE == 4) ? 4096 : (MODE == 5 ? 128 : 2048);
  constexpr int K   = (MODE == 4) ? 1024 : (MODE == 5 ? 128 : 2048);

  __shared__ __align__(16) char smem[16384];  // A tile [128][32]bf16, B tile [128][32]bf16

  const int t = threadIdx.x;
  const int u = t & 63;
  const int wid = t >> 6;
  const int wr = wid >> 1, wc = wid & 1;

  const u16* Au;
  const u16* Bu;
  if constexpr (MODE <= 3 || MODE == 6) {
    Au = Ab + (size_t)blockIdx.y * 128 * 2048;
    Bu = Bb + (size_t)blockIdx.x * 128 * 2048;
  } else if constexpr (MODE == 4) {
    Au = Ab + (size_t)blockIdx.y * 524288 + blockIdx.x * 1024;
    Bu = Bb + (size_t)blockIdx.y * 524288 + blockIdx.x * 1024;
  } else {  // MODE 5
    int bh = blockIdx.y, b = bh >> 4, h = bh & 15;
    Au = Ab + ((size_t)(b * 4096 + blockIdx.x * 128)) * 2048 + h * 128;
    Bu = Bb + (size_t)bh * 16384;
  }

  const int srow = t >> 2;          // staging row 0..63 (+64 for 2nd issue)
  const int scolb = (t & 3) * 16;   // staging byte col within 64B row

  f32x4 acc[4][4];
#pragma unroll
  for (int i = 0; i < 4; ++i)
#pragma unroll
    for (int j = 0; j < 4; ++j) acc[i][j] = (f32x4){0.f, 0.f, 0.f, 0.f};

  const int aoff = (wr * 64 + (u & 15)) * 64 + (u >> 4) * 16;
  const int boff = 8192 + (wc * 64 + (u & 15)) * 64 + (u >> 4) * 16;

  for (int k0 = 0; k0 < K; k0 += 32) {
    const char* ga = (const char*)Au + ((size_t)srow * ldA + k0) * 2 + scolb;
    const char* gb = (const char*)Bu + ((size_t)srow * ldB + k0) * 2 + scolb;
    gl_lds16(ga, smem + t * 16);
    gl_lds16(ga + (size_t)64 * ldA * 2, smem + 4096 + t * 16);
    gl_lds16(gb, smem + 8192 + t * 16);
    gl_lds16(gb + (size_t)64 * ldB * 2, smem + 12288 + t * 16);
    __syncthreads();

    bf16x8 af[4], bfr[4];
#pragma unroll
    for (int mi = 0; mi < 4; ++mi) af[mi] = *(const bf16x8*)(smem + aoff + mi * 1024);
#pragma unroll
    for (int ni = 0; ni < 4; ++ni) bfr[ni] = *(const bf16x8*)(smem + boff + ni * 1024);
#pragma unroll
    for (int mi = 0; mi < 4; ++mi)
#pragma unroll
      for (int ni = 0; ni < 4; ++ni)
        acc[mi][ni] = __builtin_amdgcn_mfma_f32_16x16x32_bf16(af[mi], bfr[ni], acc[mi][ni], 0, 0, 0);
    __syncthreads();
  }

  // epilogue: acc[mi][ni][j] -> (row = wr*64+mi*16+(u>>4)*4+j, col = wc*64+ni*16+(u&15))
#pragma unroll
  for (int mi = 0; mi < 4; ++mi)
#pragma unroll
    for (int ni = 0; ni < 4; ++ni)
#pragma unroll
      for (int j = 0; j < 4; ++j) {
        float v = acc[mi][ni][j];
        int ml = wr * 64 + mi * 16 + ((u >> 4) << 2) + j;
        int nl = wc * 64 + ni * 16 + (u & 15);
        if constexpr (MODE == 0) {  // Q
          size_t m = (size_t)blockIdx.y * 128 + ml, n = (size_t)blockIdx.x * 128 + nl;
          ((u16*)Cb)[m * 2048 + n] = f2bf(fmaxf(v, 0.f) * INV_SCALE);
        } else if constexpr (MODE == 1 || MODE == 2) {  // KT / VT transposed per-head
          int m = blockIdx.y * 128 + ml, n = blockIdx.x * 128 + nl;
          float q = (MODE == 1) ? fmaxf(v, 0.f) * INV_SCALE : v;
          int bh = ((m >> 12) << 4) | (n >> 7);
          ((u16*)Cb)[(size_t)bh * 524288 + (size_t)(n & 127) * 4096 + (m & 4095)] = f2bf(q);
        } else if constexpr (MODE == 3) {  // U = silu
          size_t m = (size_t)blockIdx.y * 128 + ml, n = (size_t)blockIdx.x * 128 + nl;
          float s = v * (1.f / (1.f + __expf(-v)));
          ((u16*)Cb)[m * 2048 + n] = f2bf(s);
        } else if constexpr (MODE == 4) {  // KV partial fp32: [chunk][bh][e][d]
          ((float*)Cb)[((size_t)blockIdx.x * 64 + blockIdx.y) * 16384 + ml * 128 + nl] = v;
        } else if constexpr (MODE == 5) {  // Oraw
          int bh = blockIdx.y, b = bh >> 4, h = bh & 15;
          size_t row = (size_t)b * 4096 + blockIdx.x * 128 + ml;
          ((u16*)Cb)[row * 2048 + h * 128 + nl] = f2bf(v);
        } else {  // MODE 6: final fp32
          size_t m = (size_t)blockIdx.y * 128 + ml, n = (size_t)blockIdx.x * 128 + nl;
          ((float*)Cb)[m * 2048 + n] = v;
        }
      }
}

// ---------------- KV partial reduce: 4 chunks fp32 -> bf16 ----------------
__global__ __launch_bounds__(256) void kv_reduce(const float* __restrict__ part,
                                                 u16* __restrict__ kvt) {
  int i = blockIdx.x * 256 + threadIdx.x;  // 64*128*128 = 1048576 elements
  float s = part[i] + part[i + 1048576] + part[i + 2097152] + part[i + 3145728];
  kvt[i] = f2bf(s);
}

// ---------------- SRMS norm * U: one wave per (l, h) ----------------
__global__ __launch_bounds__(256) void srms_mul(const u16* __restrict__ Oraw,
                                                const u16* __restrict__ Ub,
                                                u16* __restrict__ Ob) {
  int g = blockIdx.x * 4 + (threadIdx.x >> 6);  // (l,h) group, 262144 total
  int u = threadIdx.x & 63;
  int l = g >> 4, h = g & 15;
  size_t base = (size_t)l * 2048 + h * 128;
  u32 v = ((const u32*)(Oraw + base))[u];  // 2 bf16 per lane
  float a = bf2f((u16)(v & 0xffff)), b = bf2f((u16)(v >> 16));
  float ss = a * a + b * b;
#pragma unroll
  for (int off = 32; off; off >>= 1) ss += __shfl_xor(ss, off);
  float norm = sqrtf(ss * (1.0f / 128.0f));
  norm = fmaxf(norm, 1e-12f);
  float inv = 1.0f / norm;
  u32 uv = ((const u32*)(Ub + base))[u];
  float ua = bf2f((u16)(uv & 0xffff)), ub = bf2f((u16)(uv >> 16));
  u32 o = (u32)f2bf(a * inv * ua) | ((u32)f2bf(b * inv * ub) << 16);
  ((u32*)(Ob + base))[u] = o;
}

extern "C" void kernel_launch(void* const* d_in, const int* in_sizes, int n_in,
                              void* d_out, int out_size, void* d_ws, size_t ws_size,
                              hipStream_t stream) {
  (void)in_sizes; (void)n_in; (void)out_size; (void)ws_size;
  const float* x  = (const float*)d_in[0];
  const float* wq = (const float*)d_in[1];
  const float* wk = (const float*)d_in[2];
  const float* wv = (const float*)d_in[3];
  const float* wu = (const float*)d_in[4];
  const float* wo = (const float*)d_in[5];

  char* ws = (char*)d_ws;
  u16* wb   = (u16*)(ws + 0);             // 8 MiB, reused for each weight
  u16* xb   = (u16*)(ws + 8388608);       // 64 MiB (reused as Ob later)
  u16* Qb   = (u16*)(ws + 75497472);      // 64 MiB
  u16* Ub   = (u16*)(ws + 142606336);     // 64 MiB
  float* KVp = (float*)(ws + 209715200);  // 16 MiB: 4x64x128x128 fp32
  u16* KVT  = (u16*)(ws + 226492416);     // 2 MiB: 64x128x128 bf16 (end: 228,589,568 B)
  u16* Ob   = xb;                         // alias: xb dead after projections
  u16* KT   = (u16*)d_out;                // d_out scratch (first 64 MiB)
  u16* VT   = (u16*)d_out + 33554432;     // d_out scratch (second 64 MiB)
  u16* Oraw = (u16*)d_out;                // KT region, dead after KV stage

  // x -> bf16
  cvt_f32_bf16<<<4096, 256, 0, stream>>>((const float4*)x, xb, 8388608);

  dim3 gproj(16, 128);
  // Q
  cvt_f32_bf16<<<4096, 256, 0, stream>>>((const float4*)wq, wb, 1048576);
  gemm128<0><<<gproj, 256, 0, stream>>>(xb, wb, Qb);
  // K -> KT
  cvt_f32_bf16<<<4096, 256, 0, stream>>>((const float4*)wk, wb, 1048576);
  gemm128<1><<<gproj, 256, 0, stream>>>(xb, wb, KT);
  // V -> VT
  cvt_f32_bf16<<<4096, 256, 0, stream>>>((const float4*)wv, wb, 1048576);
  gemm128<2><<<gproj, 256, 0, stream>>>(xb, wb, VT);
  // U
  cvt_f32_bf16<<<4096, 256, 0, stream>>>((const float4*)wu, wb, 1048576);
  gemm128<3><<<gproj, 256, 0, stream>>>(xb, wb, Ub);

  // KVT[bh][e][d] = sum_l VT[e][l] * KT[d][l]
  gemm128<4><<<dim3(4, 64), 256, 0, stream>>>(VT, KT, KVp);
  kv_reduce<<<4096, 256, 0, stream>>>(KVp, KVT);

  // Oraw = Q @ KVT^T (per head) -> d_out KT region (KT/VT dead now)
  gemm128<5><<<dim3(32, 64), 256, 0, stream>>>(Qb, KVT, Oraw);

  // SRMS norm * U -> Ob (= xb)
  srms_mul<<<65536, 256, 0, stream>>>(Oraw, Ub, Ob);

  // out = Ob @ wo^T (fp32, full overwrite of d_out)
  cvt_f32_bf16<<<4096, 256, 0, stream>>>((const float4*)wo, wb, 1048576);
  gemm128<6><<<gproj, 256, 0, stream>>>(Ob, wb, (float*)d_out);
}

// Round 5
// 834.014 us; speedup vs baseline: 1.2593x; 1.2593x over previous
//
#include <hip/hip_runtime.h>
#include <hip/hip_bf16.h>

// MHRetention (B=4, L=4096, EMB=2048, H=16, hd=128), fp32 in/out, bf16 MFMA compute.
// Big GEMMs (modes 0,1,2,3,6): 256x256 tile, 8 waves, BK=32, triple-buffered LDS,
// 2-phase-per-K-tile schedule with counted vmcnt (T3+T4), conflict-free XOR swizzle (T2),
// setprio around MFMA (T5), XCD-bijective block swizzle (T1).
// Round-4 fix: B tiles now staged at 49152+regoff (were overwriting the A region
// while LDB read uninitialized LDS -> NaN).
// Small GEMMs (modes 4,5) keep the proven 128x128 kernel.

typedef unsigned int u32;
typedef unsigned short u16;
typedef __bf16 bf16x8 __attribute__((ext_vector_type(8)));
typedef float f32x4 __attribute__((ext_vector_type(4)));

__device__ __forceinline__ u16 f2bf(float f) {
  u32 u = __float_as_uint(f);
  u = (u + 0x7fffu + ((u >> 16) & 1u)) >> 16;
  return (u16)u;
}
__device__ __forceinline__ float bf2f(u16 s) { return __uint_as_float(((u32)s) << 16); }

__device__ __forceinline__ void gl_lds16(const void* g, void* l) {
  __builtin_amdgcn_global_load_lds((const __attribute__((address_space(1))) void*)g,
                                   (__attribute__((address_space(3))) void*)l, 16, 0, 0);
}

__device__ __forceinline__ void bar() {
  asm volatile("" ::: "memory");
  __builtin_amdgcn_s_barrier();
  asm volatile("" ::: "memory");
}

#define INV_SCALE 0.08838834764831845f  // 1/sqrt(128)

// ---------------- fp32 -> bf16 conversion ----------------
__global__ __launch_bounds__(256) void cvt_f32_bf16(const float4* __restrict__ in,
                                                    u16* __restrict__ out, int n4) {
  int i = blockIdx.x * 256 + threadIdx.x;
  int stride = gridDim.x * 256;
  for (; i < n4; i += stride) {
    float4 v = in[i];
    u32 lo = (u32)f2bf(v.x) | ((u32)f2bf(v.y) << 16);
    u32 hi = (u32)f2bf(v.z) | ((u32)f2bf(v.w) << 16);
    ((uint2*)out)[i] = make_uint2(lo, hi);
  }
}

// ================= 256x256 big GEMM (M=16384, N=2048, K=2048) =================
// C[m][n] = sum_k A[m][k]*B[n][k]; MODE: 0=Q,1=KT,2=VT,3=U,6=final fp32
template <int MODE>
__global__ __launch_bounds__(512, 2) void gemm256(const u16* __restrict__ Ab,
                                                  const u16* __restrict__ Bb,
                                                  void* __restrict__ Cb) {
  // LDS: A regions 3 x 16384 B at 0; B regions 3 x 16384 B at 49152. 96 KiB total.
  __shared__ __align__(16) char smem[98304];

  const int t = threadIdx.x;
  const int u = t & 63;
  const int wid = t >> 6;          // 0..7
  const int wm = wid >> 2;         // 0..1 (M half)
  const int wn = wid & 3;          // 0..3 (N quarter)

  // XCD-bijective swizzle: 512 blocks, 512 % 8 == 0
  const int wgid = blockIdx.x;
  const int swz = (wgid & 7) * 64 + (wgid >> 3);
  const int mt = swz >> 3;         // 0..63
  const int nt = swz & 7;          // 0..7

  const u16* Asrc = Ab + (size_t)mt * 256 * 2048;
  const u16* Bsrc = Bb + (size_t)nt * 256 * 2048;

  // staging: thread t covers region rows {srow, 128+srow}, 16B granule (t&3),
  // source col pre-swizzled by the involution  g ^= (row>>1)&3  (granule units)
  const int srow = t >> 2;                              // 0..127
  const int scol = ((t & 3) ^ ((t >> 3) & 3)) * 8;      // element offset in K

  // fragment reads: row = rowbase + (u&15), byte col = ((u>>4)*16) ^ (((row>>1)&3)<<4)
  const int cread = (((u >> 4) * 16) ^ (((u >> 1) & 3) << 4));
  const int arowb = (wm * 128 + (u & 15)) * 64;  // byte row base (mi=0)
  const int browb = (wn * 64 + (u & 15)) * 64;   // byte row base (ni=0)

#define STAGE(srcp, regoff, kb)                                                      \
  {                                                                                  \
    gl_lds16((const void*)((srcp) + ((size_t)srow * 2048 + (kb) + scol)),            \
             smem + (regoff) + wid * 1024);                                          \
    gl_lds16((const void*)((srcp) + ((size_t)(128 + srow) * 2048 + (kb) + scol)),    \
             smem + (regoff) + 8192 + wid * 1024);                                   \
  }

#define LDA(mi, off) (*(const bf16x8*)(smem + (off) + arowb + (mi) * 1024 + cread))
#define LDB(ni, off) (*(const bf16x8*)(smem + 49152 + (off) + browb + (ni) * 1024 + cread))

  f32x4 acc[8][4];
#pragma unroll
  for (int i = 0; i < 8; ++i)
#pragma unroll
    for (int j = 0; j < 4; ++j) acc[i][j] = (f32x4){0.f, 0.f, 0.f, 0.f};

  // prologue: stage tiles 0 and 1 (A at regoff, B at 49152+regoff)
  STAGE(Asrc, 0, 0);
  STAGE(Bsrc, 49152 + 0, 0);
  STAGE(Asrc, 16384, 32);
  STAGE(Bsrc, 49152 + 16384, 32);
  asm volatile("s_waitcnt vmcnt(4)" ::: "memory");  // tile0 landed; tile1 in flight
  bar();

  int cur = 0, nxt = 16384, stg = 32768;
  for (int tk = 0; tk < 64; ++tk) {
    const int kb = (tk + 2) * 32;
    // ---- phase 1: mi 0..3 ----
    bf16x8 b0 = LDB(0, cur), b1 = LDB(1, cur), b2 = LDB(2, cur), b3 = LDB(3, cur);
    bf16x8 a0 = LDA(0, cur), a1 = LDA(1, cur), a2 = LDA(2, cur), a3 = LDA(3, cur);
    if (tk < 62) STAGE(Asrc, stg, kb);
    bar();
    __builtin_amdgcn_s_setprio(1);
#define MFMA_ROW(ai, m_i)                                                              \
    acc[m_i][0] = __builtin_amdgcn_mfma_f32_16x16x32_bf16(ai, b0, acc[m_i][0], 0, 0, 0); \
    acc[m_i][1] = __builtin_amdgcn_mfma_f32_16x16x32_bf16(ai, b1, acc[m_i][1], 0, 0, 0); \
    acc[m_i][2] = __builtin_amdgcn_mfma_f32_16x16x32_bf16(ai, b2, acc[m_i][2], 0, 0, 0); \
    acc[m_i][3] = __builtin_amdgcn_mfma_f32_16x16x32_bf16(ai, b3, acc[m_i][3], 0, 0, 0);
    MFMA_ROW(a0, 0) MFMA_ROW(a1, 1) MFMA_ROW(a2, 2) MFMA_ROW(a3, 3)
    __builtin_amdgcn_s_setprio(0);
    bar();
    // ---- phase 2: mi 4..7 ----
    a0 = LDA(4, cur); a1 = LDA(5, cur); a2 = LDA(6, cur); a3 = LDA(7, cur);
    if (tk < 62) STAGE(Bsrc, 49152 + stg, kb);
    bar();
    __builtin_amdgcn_s_setprio(1);
    MFMA_ROW(a0, 4) MFMA_ROW(a1, 5) MFMA_ROW(a2, 6) MFMA_ROW(a3, 7)
    __builtin_amdgcn_s_setprio(0);
    if (tk < 62) {
      asm volatile("s_waitcnt vmcnt(4)" ::: "memory");  // tile tk+1 landed; tk+2 in flight
    } else {
      asm volatile("s_waitcnt vmcnt(0)" ::: "memory");
    }
    bar();
    int tmp = cur; cur = nxt; nxt = stg; stg = tmp;
  }
#undef MFMA_ROW
#undef STAGE
#undef LDA
#undef LDB

  // epilogue: frag (mi,ni) elem jj -> m = mbase+mi*16+(u>>4)*4+jj, n = nbase+ni*16+(u&15)
  const int mbase = mt * 256 + wm * 128;
  const int nbase = nt * 256 + wn * 64;
#pragma unroll
  for (int mi = 0; mi < 8; ++mi)
#pragma unroll
    for (int ni = 0; ni < 4; ++ni)
#pragma unroll
      for (int jj = 0; jj < 4; ++jj) {
        float v = acc[mi][ni][jj];
        int m = mbase + mi * 16 + ((u >> 4) << 2) + jj;
        int n = nbase + ni * 16 + (u & 15);
        if constexpr (MODE == 0) {  // Q
          ((u16*)Cb)[(size_t)m * 2048 + n] = f2bf(fmaxf(v, 0.f) * INV_SCALE);
        } else if constexpr (MODE == 1 || MODE == 2) {  // KT / VT per-head transposed
          float q = (MODE == 1) ? fmaxf(v, 0.f) * INV_SCALE : v;
          int bh = ((m >> 12) << 4) | (n >> 7);
          ((u16*)Cb)[(size_t)bh * 524288 + (size_t)(n & 127) * 4096 + (m & 4095)] = f2bf(q);
        } else if constexpr (MODE == 3) {  // U = silu
          float s = v * (1.f / (1.f + __expf(-v)));
          ((u16*)Cb)[(size_t)m * 2048 + n] = f2bf(s);
        } else {  // MODE 6: final fp32
          ((float*)Cb)[(size_t)m * 2048 + n] = v;
        }
      }
}

// ================= 128x128 kernel for the small KV / O stages =================
// MODE: 4=KV partial (fp32), 5=O (bf16)
template <int MODE>
__global__ __launch_bounds__(256) void gemm128(const u16* __restrict__ Ab,
                                               const u16* __restrict__ Bb,
                                               void* __restrict__ Cb) {
  constexpr int ldA = (MODE == 4) ? 4096 : 2048;
  constexpr int ldB = (MODE == 4) ? 4096 : 128;
  constexpr int K   = (MODE == 4) ? 1024 : 128;

  __shared__ __align__(16) char smem[16384];

  const int t = threadIdx.x;
  const int u = t & 63;
  const int wid = t >> 6;
  const int wr = wid >> 1, wc = wid & 1;

  const u16* Au;
  const u16* Bu;
  if constexpr (MODE == 4) {
    Au = Ab + (size_t)blockIdx.y * 524288 + blockIdx.x * 1024;
    Bu = Bb + (size_t)blockIdx.y * 524288 + blockIdx.x * 1024;
  } else {  // MODE 5
    int bh = blockIdx.y, b = bh >> 4, h = bh & 15;
    Au = Ab + ((size_t)(b * 4096 + blockIdx.x * 128)) * 2048 + h * 128;
    Bu = Bb + (size_t)bh * 16384;
  }

  const int srow = t >> 2;
  const int scolb = (t & 3) * 16;

  f32x4 acc[4][4];
#pragma unroll
  for (int i = 0; i < 4; ++i)
#pragma unroll
    for (int j = 0; j < 4; ++j) acc[i][j] = (f32x4){0.f, 0.f, 0.f, 0.f};

  const int aoff = (wr * 64 + (u & 15)) * 64 + (u >> 4) * 16;
  const int boff = 8192 + (wc * 64 + (u & 15)) * 64 + (u >> 4) * 16;

  for (int k0 = 0; k0 < K; k0 += 32) {
    const char* ga = (const char*)Au + ((size_t)srow * ldA + k0) * 2 + scolb;
    const char* gb = (const char*)Bu + ((size_t)srow * ldB + k0) * 2 + scolb;
    gl_lds16(ga, smem + t * 16);
    gl_lds16(ga + (size_t)64 * ldA * 2, smem + 4096 + t * 16);
    gl_lds16(gb, smem + 8192 + t * 16);
    gl_lds16(gb + (size_t)64 * ldB * 2, smem + 12288 + t * 16);
    __syncthreads();

    bf16x8 af[4], bfr[4];
#pragma unroll
    for (int mi = 0; mi < 4; ++mi) af[mi] = *(const bf16x8*)(smem + aoff + mi * 1024);
#pragma unroll
    for (int ni = 0; ni < 4; ++ni) bfr[ni] = *(const bf16x8*)(smem + boff + ni * 1024);
#pragma unroll
    for (int mi = 0; mi < 4; ++mi)
#pragma unroll
      for (int ni = 0; ni < 4; ++ni)
        acc[mi][ni] = __builtin_amdgcn_mfma_f32_16x16x32_bf16(af[mi], bfr[ni], acc[mi][ni], 0, 0, 0);
    __syncthreads();
  }

#pragma unroll
  for (int mi = 0; mi < 4; ++mi)
#pragma unroll
    for (int ni = 0; ni < 4; ++ni)
#pragma unroll
      for (int j = 0; j < 4; ++j) {
        float v = acc[mi][ni][j];
        int ml = wr * 64 + mi * 16 + ((u >> 4) << 2) + j;
        int nl = wc * 64 + ni * 16 + (u & 15);
        if constexpr (MODE == 4) {  // KV partial fp32: [chunk][bh][e][d]
          ((float*)Cb)[((size_t)blockIdx.x * 64 + blockIdx.y) * 16384 + ml * 128 + nl] = v;
        } else {  // MODE 5: Oraw
          int bh = blockIdx.y, b = bh >> 4, h = bh & 15;
          size_t row = (size_t)b * 4096 + blockIdx.x * 128 + ml;
          ((u16*)Cb)[row * 2048 + h * 128 + nl] = f2bf(v);
        }
      }
}

// ---------------- KV partial reduce: 4 chunks fp32 -> bf16 ----------------
__global__ __launch_bounds__(256) void kv_reduce(const float* __restrict__ part,
                                                 u16* __restrict__ kvt) {
  int i = blockIdx.x * 256 + threadIdx.x;  // 64*128*128 = 1048576 elements
  float s = part[i] + part[i + 1048576] + part[i + 2097152] + part[i + 3145728];
  kvt[i] = f2bf(s);
}

// ---------------- SRMS norm * U: one wave per (l, h) ----------------
__global__ __launch_bounds__(256) void srms_mul(const u16* __restrict__ Oraw,
                                                const u16* __restrict__ Ub,
                                                u16* __restrict__ Ob) {
  int g = blockIdx.x * 4 + (threadIdx.x >> 6);
  int u = threadIdx.x & 63;
  int l = g >> 4, h = g & 15;
  size_t base = (size_t)l * 2048 + h * 128;
  u32 v = ((const u32*)(Oraw + base))[u];
  float a = bf2f((u16)(v & 0xffff)), b = bf2f((u16)(v >> 16));
  float ss = a * a + b * b;
#pragma unroll
  for (int off = 32; off; off >>= 1) ss += __shfl_xor(ss, off);
  float norm = sqrtf(ss * (1.0f / 128.0f));
  norm = fmaxf(norm, 1e-12f);
  float inv = 1.0f / norm;
  u32 uv = ((const u32*)(Ub + base))[u];
  float ua = bf2f((u16)(uv & 0xffff)), ub = bf2f((u16)(uv >> 16));
  u32 o = (u32)f2bf(a * inv * ua) | ((u32)f2bf(b * inv * ub) << 16);
  ((u32*)(Ob + base))[u] = o;
}

extern "C" void kernel_launch(void* const* d_in, const int* in_sizes, int n_in,
                              void* d_out, int out_size, void* d_ws, size_t ws_size,
                              hipStream_t stream) {
  (void)in_sizes; (void)n_in; (void)out_size; (void)ws_size;
  const float* x  = (const float*)d_in[0];
  const float* wq = (const float*)d_in[1];
  const float* wk = (const float*)d_in[2];
  const float* wv = (const float*)d_in[3];
  const float* wu = (const float*)d_in[4];
  const float* wo = (const float*)d_in[5];

  char* ws = (char*)d_ws;
  u16* wb   = (u16*)(ws + 0);             // 8 MiB, reused for each weight
  u16* xb   = (u16*)(ws + 8388608);       // 64 MiB (reused as Ob later)
  u16* Qb   = (u16*)(ws + 75497472);      // 64 MiB
  u16* Ub   = (u16*)(ws + 142606336);     // 64 MiB
  float* KVp = (float*)(ws + 209715200);  // 16 MiB: 4x64x128x128 fp32
  u16* KVT  = (u16*)(ws + 226492416);     // 2 MiB (end: 228,589,568 B)
  u16* Ob   = xb;                         // alias: xb dead after projections
  u16* KT   = (u16*)d_out;                // d_out scratch (first 64 MiB)
  u16* VT   = (u16*)d_out + 33554432;     // d_out scratch (second 64 MiB)
  u16* Oraw = (u16*)d_out;                // KT region, dead after KV stage

  // x -> bf16
  cvt_f32_bf16<<<4096, 256, 0, stream>>>((const float4*)x, xb, 8388608);

  // Q
  cvt_f32_bf16<<<4096, 256, 0, stream>>>((const float4*)wq, wb, 1048576);
  gemm256<0><<<512, 512, 0, stream>>>(xb, wb, Qb);
  // K -> KT
  cvt_f32_bf16<<<4096, 256, 0, stream>>>((const float4*)wk, wb, 1048576);
  gemm256<1><<<512, 512, 0, stream>>>(xb, wb, KT);
  // V -> VT
  cvt_f32_bf16<<<4096, 256, 0, stream>>>((const float4*)wv, wb, 1048576);
  gemm256<2><<<512, 512, 0, stream>>>(xb, wb, VT);
  // U
  cvt_f32_bf16<<<4096, 256, 0, stream>>>((const float4*)wu, wb, 1048576);
  gemm256<3><<<512, 512, 0, stream>>>(xb, wb, Ub);

  // KVT[bh][e][d] = sum_l VT[e][l] * KT[d][l]
  gemm128<4><<<dim3(4, 64), 256, 0, stream>>>(VT, KT, KVp);
  kv_reduce<<<4096, 256, 0, stream>>>(KVp, KVT);

  // Oraw = Q @ KVT^T (per head) -> d_out KT region
  gemm128<5><<<dim3(32, 64), 256, 0, stream>>>(Qb, KVT, Oraw);

  // SRMS norm * U -> Ob (= xb)
  srms_mul<<<65536, 256, 0, stream>>>(Oraw, Ub, Ob);

  // out = Ob @ wo^T (fp32, full overwrite of d_out)
  cvt_f32_bf16<<<4096, 256, 0, stream>>>((const float4*)wo, wb, 1048576);
  gemm256<6><<<512, 512, 0, stream>>>(Ob, wb, (float*)d_out);
}

// Round 6
// 771.540 us; speedup vs baseline: 1.3613x; 1.0810x over previous
//
#include <hip/hip_runtime.h>
#include <hip/hip_bf16.h>

// MHRetention (B=4, L=4096, EMB=2048, H=16, hd=128), fp32 in/out, bf16 MFMA compute.
// Big GEMMs (modes 0,1,2,3,6): m201-style 256x256 tile, BK=64, 8 waves (2Mx4N),
// 128 KiB double-buffered LDS, 8 phases per 2 K-tiles, 1 half-tile staged per phase
// into the half that died 2 phases earlier, counted vmcnt(4) at phases 4/8 only,
// XOR swizzle (granule ^= row&7) on both stage-source and read, setprio around MFMA,
// XCD-bijective block swizzle. Small GEMMs (modes 4,5) keep the proven 128x128 kernel.

typedef unsigned int u32;
typedef unsigned short u16;
typedef __bf16 bf16x8 __attribute__((ext_vector_type(8)));
typedef float f32x4 __attribute__((ext_vector_type(4)));

__device__ __forceinline__ u16 f2bf(float f) {
  u32 u = __float_as_uint(f);
  u = (u + 0x7fffu + ((u >> 16) & 1u)) >> 16;
  return (u16)u;
}
__device__ __forceinline__ float bf2f(u16 s) { return __uint_as_float(((u32)s) << 16); }

__device__ __forceinline__ void gl_lds16(const void* g, void* l) {
  __builtin_amdgcn_global_load_lds((const __attribute__((address_space(1))) void*)g,
                                   (__attribute__((address_space(3))) void*)l, 16, 0, 0);
}

__device__ __forceinline__ void bar() {
  asm volatile("" ::: "memory");
  __builtin_amdgcn_s_barrier();
  asm volatile("" ::: "memory");
}

#define INV_SCALE 0.08838834764831845f  // 1/sqrt(128)

// ---------------- fp32 -> bf16 conversion ----------------
__global__ __launch_bounds__(256) void cvt_f32_bf16(const float4* __restrict__ in,
                                                    u16* __restrict__ out, int n4) {
  int i = blockIdx.x * 256 + threadIdx.x;
  int stride = gridDim.x * 256;
  for (; i < n4; i += stride) {
    float4 v = in[i];
    u32 lo = (u32)f2bf(v.x) | ((u32)f2bf(v.y) << 16);
    u32 hi = (u32)f2bf(v.z) | ((u32)f2bf(v.w) << 16);
    ((uint2*)out)[i] = make_uint2(lo, hi);
  }
}

// ================= 256x256 big GEMM (M=16384, N=2048, K=2048) =================
// C[m][n] = sum_k A[m][k]*B[n][k]; MODE: 0=Q,1=KT,2=VT,3=U,6=final fp32
// LDS map (131072 B): buf b at b*65536: A0 @ +0, A1 @ +16384, B0 @ +32768, B1 @ +49152.
// Tiles t=0..31 (BK=64): tile t lives in buf[t&1]. Iter i computes tiles 2i (buf0,
// phases 1-4) and 2i+1 (buf1, phases 5-8).
// Stage schedule (tile, half -> phase): A0(2i+1)@P1, A1(2i+1)@P2, B0(2i+2)@P3,
// B1(2i+2)@P4, A0(2i+2)@P5, A1(2i+2)@P6, B0(2i+3)@P7, B1(2i+3)@P8.
// Each target half is dead (last ds_read >=1 barrier earlier). vmcnt(4)+bar at P4
// publishes tile 2i+1; at P8 publishes tile 2i+2. Last iter: P4 uses vmcnt(0).
template <int MODE>
__global__ __launch_bounds__(512, 2) void gemm256(const u16* __restrict__ Ab,
                                                  const u16* __restrict__ Bb,
                                                  void* __restrict__ Cb) {
  __shared__ __align__(16) char smem[131072];

  const int t = threadIdx.x;
  const int u = t & 63;
  const int wid = t >> 6;          // 0..7
  const int wm = wid >> 2;         // 0..1 (M half)
  const int wn = wid & 3;          // 0..3 (N quarter)

  // XCD-bijective swizzle: 512 blocks, 512 % 8 == 0
  const int wgid = blockIdx.x;
  const int swz = (wgid & 7) * 64 + (wgid >> 3);
  const int mt = swz >> 3;         // 0..63
  const int nt = swz & 7;          // 0..7

  const u16* Asrc = Ab + (size_t)mt * 256 * 2048;
  const u16* Bsrc = Bb + (size_t)nt * 256 * 2048;

  // staging: thread t covers rows {srow, 64+srow} of a 128-row half-tile, granule t&7.
  // source granule = (t&7) ^ (row&7)  (involution; row&7 == srow&7 for both loads)
  const int srow = t >> 3;                         // 0..63
  const int scol = ((t & 7) ^ (srow & 7)) * 8;     // element col offset

  // reads: row&7 == u&7; granule(kk) = (kk*4 + (u>>4)) ^ (u&7)
  const int ard = wm * 16384;
  const int brd = 32768 + (wn >> 1) * 16384;
  const int arow = (u & 15) * 128;                       // + mi*2048 bytes
  const int brow = ((wn & 1) * 64 + (u & 15)) * 128;     // + ni*2048 bytes
  const int cr0 = ((u >> 4) ^ (u & 7)) * 16;             // kk=0
  const int cr1 = ((4 + (u >> 4)) ^ (u & 7)) * 16;       // kk=1

#define STG(base, R, kb, reg)                                                            \
  {                                                                                      \
    gl_lds16((base) + (size_t)((R) + srow) * 2048 + (kb) + scol, smem + (reg) + t * 16); \
    gl_lds16((base) + (size_t)((R) + 64 + srow) * 2048 + (kb) + scol,                    \
             smem + (reg) + 8192 + t * 16);                                              \
  }

#define LDA(buf, mi, cr) (*(const bf16x8*)(smem + (buf) + ard + arow + (mi) * 2048 + (cr)))
#define LDB(buf, ni, cr) (*(const bf16x8*)(smem + (buf) + brd + brow + (ni) * 2048 + (cr)))
#define MFMA(d, a_, b_) d = __builtin_amdgcn_mfma_f32_16x16x32_bf16(a_, b_, d, 0, 0, 0)
// 16 MFMA: quadrant (MB..MB+3) x (NB..NB+1), both kk slices
#define QUAD(MB, NB, B_0, B_1, B_2, B_3)                              \
  MFMA(acc[MB + 0][NB + 0], a00, B_0); MFMA(acc[MB + 0][NB + 0], a01, B_1); \
  MFMA(acc[MB + 0][NB + 1], a00, B_2); MFMA(acc[MB + 0][NB + 1], a01, B_3); \
  MFMA(acc[MB + 1][NB + 0], a10, B_0); MFMA(acc[MB + 1][NB + 0], a11, B_1); \
  MFMA(acc[MB + 1][NB + 1], a10, B_2); MFMA(acc[MB + 1][NB + 1], a11, B_3); \
  MFMA(acc[MB + 2][NB + 0], a20, B_0); MFMA(acc[MB + 2][NB + 0], a21, B_1); \
  MFMA(acc[MB + 2][NB + 1], a20, B_2); MFMA(acc[MB + 2][NB + 1], a21, B_3); \
  MFMA(acc[MB + 3][NB + 0], a30, B_0); MFMA(acc[MB + 3][NB + 0], a31, B_1); \
  MFMA(acc[MB + 3][NB + 1], a30, B_2); MFMA(acc[MB + 3][NB + 1], a31, B_3);

  f32x4 acc[8][4];
#pragma unroll
  for (int i = 0; i < 8; ++i)
#pragma unroll
    for (int j = 0; j < 4; ++j) acc[i][j] = (f32x4){0.f, 0.f, 0.f, 0.f};

  bf16x8 a00, a01, a10, a11, a20, a21, a30, a31;
  bf16x8 b00, b01, b10, b11, b20, b21, b30, b31;

  // prologue: tile0 all halves + tile1 B halves (12 loads); vmcnt(4) -> tile0 landed
  STG(Bsrc, 0, 0, 32768) STG(Bsrc, 128, 0, 49152)
  STG(Asrc, 0, 0, 0) STG(Asrc, 128, 0, 16384)
  STG(Bsrc, 0, 64, 65536 + 32768) STG(Bsrc, 128, 64, 65536 + 49152)
  asm volatile("s_waitcnt vmcnt(4)" ::: "memory");
  bar();

  for (int i = 0; i < 16; ++i) {
    const int kA1 = (2 * i + 1) * 64;
    const int kT2 = (2 * i + 2) * 64;
    const int kB3 = (2 * i + 3) * 64;
    // ---- P1: buf0 A(mi0-3), B(ni0-1); stage A0(2i+1)->buf1 ----
    a00 = LDA(0, 0, cr0); a01 = LDA(0, 0, cr1); a10 = LDA(0, 1, cr0); a11 = LDA(0, 1, cr1);
    a20 = LDA(0, 2, cr0); a21 = LDA(0, 2, cr1); a30 = LDA(0, 3, cr0); a31 = LDA(0, 3, cr1);
    b00 = LDB(0, 0, cr0); b01 = LDB(0, 0, cr1); b10 = LDB(0, 1, cr0); b11 = LDB(0, 1, cr1);
    STG(Asrc, 0, kA1, 65536 + 0)
    bar();
    __builtin_amdgcn_s_setprio(1); QUAD(0, 0, b00, b01, b10, b11) __builtin_amdgcn_s_setprio(0);
    bar();
    // ---- P2: buf0 B(ni2-3); stage A1(2i+1)->buf1 ----
    b20 = LDB(0, 2, cr0); b21 = LDB(0, 2, cr1); b30 = LDB(0, 3, cr0); b31 = LDB(0, 3, cr1);
    STG(Asrc, 128, kA1, 65536 + 16384)
    bar();
    __builtin_amdgcn_s_setprio(1); QUAD(0, 2, b20, b21, b30, b31) __builtin_amdgcn_s_setprio(0);
    bar();
    // ---- P3: buf0 A(mi4-7); stage B0(2i+2)->buf0 ----
    a00 = LDA(0, 4, cr0); a01 = LDA(0, 4, cr1); a10 = LDA(0, 5, cr0); a11 = LDA(0, 5, cr1);
    a20 = LDA(0, 6, cr0); a21 = LDA(0, 6, cr1); a30 = LDA(0, 7, cr0); a31 = LDA(0, 7, cr1);
    if (i < 15) STG(Bsrc, 0, kT2, 32768)
    bar();
    __builtin_amdgcn_s_setprio(1); QUAD(4, 0, b00, b01, b10, b11) __builtin_amdgcn_s_setprio(0);
    bar();
    // ---- P4: stage B1(2i+2)->buf0; vmcnt publishes tile 2i+1 ----
    if (i < 15) STG(Bsrc, 128, kT2, 49152)
    bar();
    __builtin_amdgcn_s_setprio(1); QUAD(4, 2, b20, b21, b30, b31) __builtin_amdgcn_s_setprio(0);
    if (i == 15) { asm volatile("s_waitcnt vmcnt(0)" ::: "memory"); }
    else         { asm volatile("s_waitcnt vmcnt(4)" ::: "memory"); }
    bar();
    // ---- P5: buf1 A(mi0-3), B(ni0-1); stage A0(2i+2)->buf0 ----
    a00 = LDA(65536, 0, cr0); a01 = LDA(65536, 0, cr1); a10 = LDA(65536, 1, cr0); a11 = LDA(65536, 1, cr1);
    a20 = LDA(65536, 2, cr0); a21 = LDA(65536, 2, cr1); a30 = LDA(65536, 3, cr0); a31 = LDA(65536, 3, cr1);
    b00 = LDB(65536, 0, cr0); b01 = LDB(65536, 0, cr1); b10 = LDB(65536, 1, cr0); b11 = LDB(65536, 1, cr1);
    if (i < 15) STG(Asrc, 0, kT2, 0)
    bar();
    __builtin_amdgcn_s_setprio(1); QUAD(0, 0, b00, b01, b10, b11) __builtin_amdgcn_s_setprio(0);
    bar();
    // ---- P6: buf1 B(ni2-3); stage A1(2i+2)->buf0 ----
    b20 = LDB(65536, 2, cr0); b21 = LDB(65536, 2, cr1); b30 = LDB(65536, 3, cr0); b31 = LDB(65536, 3, cr1);
    if (i < 15) STG(Asrc, 128, kT2, 16384)
    bar();
    __builtin_amdgcn_s_setprio(1); QUAD(0, 2, b20, b21, b30, b31) __builtin_amdgcn_s_setprio(0);
    bar();
    // ---- P7: buf1 A(mi4-7); stage B0(2i+3)->buf1 ----
    a00 = LDA(65536, 4, cr0); a01 = LDA(65536, 4, cr1); a10 = LDA(65536, 5, cr0); a11 = LDA(65536, 5, cr1);
    a20 = LDA(65536, 6, cr0); a21 = LDA(65536, 6, cr1); a30 = LDA(65536, 7, cr0); a31 = LDA(65536, 7, cr1);
    if (i < 15) STG(Bsrc, 0, kB3, 65536 + 32768)
    bar();
    __builtin_amdgcn_s_setprio(1); QUAD(4, 0, b00, b01, b10, b11) __builtin_amdgcn_s_setprio(0);
    bar();
    // ---- P8: stage B1(2i+3)->buf1; vmcnt publishes tile 2i+2 ----
    if (i < 15) STG(Bsrc, 128, kB3, 65536 + 49152)
    bar();
    __builtin_amdgcn_s_setprio(1); QUAD(4, 2, b20, b21, b30, b31) __builtin_amdgcn_s_setprio(0);
    asm volatile("s_waitcnt vmcnt(4)" ::: "memory");
    bar();
  }
#undef QUAD
#undef MFMA
#undef LDA
#undef LDB
#undef STG

  // epilogue: frag (mi,ni) elem jj -> m = mbase+mi*16+(u>>4)*4+jj, n = nbase+ni*16+(u&15)
  const int mbase = mt * 256 + wm * 128;
  const int nbase = nt * 256 + wn * 64;
#pragma unroll
  for (int mi = 0; mi < 8; ++mi)
#pragma unroll
    for (int ni = 0; ni < 4; ++ni)
#pragma unroll
      for (int jj = 0; jj < 4; ++jj) {
        float v = acc[mi][ni][jj];
        int m = mbase + mi * 16 + ((u >> 4) << 2) + jj;
        int n = nbase + ni * 16 + (u & 15);
        if constexpr (MODE == 0) {  // Q
          ((u16*)Cb)[(size_t)m * 2048 + n] = f2bf(fmaxf(v, 0.f) * INV_SCALE);
        } else if constexpr (MODE == 1 || MODE == 2) {  // KT / VT per-head transposed
          float q = (MODE == 1) ? fmaxf(v, 0.f) * INV_SCALE : v;
          int bh = ((m >> 12) << 4) | (n >> 7);
          ((u16*)Cb)[(size_t)bh * 524288 + (size_t)(n & 127) * 4096 + (m & 4095)] = f2bf(q);
        } else if constexpr (MODE == 3) {  // U = silu
          float s = v * (1.f / (1.f + __expf(-v)));
          ((u16*)Cb)[(size_t)m * 2048 + n] = f2bf(s);
        } else {  // MODE 6: final fp32
          ((float*)Cb)[(size_t)m * 2048 + n] = v;
        }
      }
}

// ================= 128x128 kernel for the small KV / O stages =================
// MODE: 4=KV partial (fp32), 5=O (bf16)
template <int MODE>
__global__ __launch_bounds__(256) void gemm128(const u16* __restrict__ Ab,
                                               const u16* __restrict__ Bb,
                                               void* __restrict__ Cb) {
  constexpr int ldA = (MODE == 4) ? 4096 : 2048;
  constexpr int ldB = (MODE == 4) ? 4096 : 128;
  constexpr int K   = (MODE == 4) ? 1024 : 128;

  __shared__ __align__(16) char smem[16384];

  const int t = threadIdx.x;
  const int u = t & 63;
  const int wid = t >> 6;
  const int wr = wid >> 1, wc = wid & 1;

  const u16* Au;
  const u16* Bu;
  if constexpr (MODE == 4) {
    Au = Ab + (size_t)blockIdx.y * 524288 + blockIdx.x * 1024;
    Bu = Bb + (size_t)blockIdx.y * 524288 + blockIdx.x * 1024;
  } else {  // MODE 5
    int bh = blockIdx.y, b = bh >> 4, h = bh & 15;
    Au = Ab + ((size_t)(b * 4096 + blockIdx.x * 128)) * 2048 + h * 128;
    Bu = Bb + (size_t)bh * 16384;
  }

  const int srow = t >> 2;
  const int scolb = (t & 3) * 16;

  f32x4 acc[4][4];
#pragma unroll
  for (int i = 0; i < 4; ++i)
#pragma unroll
    for (int j = 0; j < 4; ++j) acc[i][j] = (f32x4){0.f, 0.f, 0.f, 0.f};

  const int aoff = (wr * 64 + (u & 15)) * 64 + (u >> 4) * 16;
  const int boff = 8192 + (wc * 64 + (u & 15)) * 64 + (u >> 4) * 16;

  for (int k0 = 0; k0 < K; k0 += 32) {
    const char* ga = (const char*)Au + ((size_t)srow * ldA + k0) * 2 + scolb;
    const char* gb = (const char*)Bu + ((size_t)srow * ldB + k0) * 2 + scolb;
    gl_lds16(ga, smem + t * 16);
    gl_lds16(ga + (size_t)64 * ldA * 2, smem + 4096 + t * 16);
    gl_lds16(gb, smem + 8192 + t * 16);
    gl_lds16(gb + (size_t)64 * ldB * 2, smem + 12288 + t * 16);
    __syncthreads();

    bf16x8 af[4], bfr[4];
#pragma unroll
    for (int mi = 0; mi < 4; ++mi) af[mi] = *(const bf16x8*)(smem + aoff + mi * 1024);
#pragma unroll
    for (int ni = 0; ni < 4; ++ni) bfr[ni] = *(const bf16x8*)(smem + boff + ni * 1024);
#pragma unroll
    for (int mi = 0; mi < 4; ++mi)
#pragma unroll
      for (int ni = 0; ni < 4; ++ni)
        acc[mi][ni] = __builtin_amdgcn_mfma_f32_16x16x32_bf16(af[mi], bfr[ni], acc[mi][ni], 0, 0, 0);
    __syncthreads();
  }

#pragma unroll
  for (int mi = 0; mi < 4; ++mi)
#pragma unroll
    for (int ni = 0; ni < 4; ++ni)
#pragma unroll
      for (int j = 0; j < 4; ++j) {
        float v = acc[mi][ni][j];
        int ml = wr * 64 + mi * 16 + ((u >> 4) << 2) + j;
        int nl = wc * 64 + ni * 16 + (u & 15);
        if constexpr (MODE == 4) {  // KV partial fp32: [chunk][bh][e][d]
          ((float*)Cb)[((size_t)blockIdx.x * 64 + blockIdx.y) * 16384 + ml * 128 + nl] = v;
        } else {  // MODE 5: Oraw
          int bh = blockIdx.y, b = bh >> 4, h = bh & 15;
          size_t row = (size_t)b * 4096 + blockIdx.x * 128 + ml;
          ((u16*)Cb)[row * 2048 + h * 128 + nl] = f2bf(v);
        }
      }
}

// ---------------- KV partial reduce: 4 chunks fp32 -> bf16 ----------------
__global__ __launch_bounds__(256) void kv_reduce(const float* __restrict__ part,
                                                 u16* __restrict__ kvt) {
  int i = blockIdx.x * 256 + threadIdx.x;  // 64*128*128 = 1048576 elements
  float s = part[i] + part[i + 1048576] + part[i + 2097152] + part[i + 3145728];
  kvt[i] = f2bf(s);
}

// ---------------- SRMS norm * U: one wave per (l, h) ----------------
__global__ __launch_bounds__(256) void srms_mul(const u16* __restrict__ Oraw,
                                                const u16* __restrict__ Ub,
                                                u16* __restrict__ Ob) {
  int g = blockIdx.x * 4 + (threadIdx.x >> 6);
  int u = threadIdx.x & 63;
  int l = g >> 4, h = g & 15;
  size_t base = (size_t)l * 2048 + h * 128;
  u32 v = ((const u32*)(Oraw + base))[u];
  float a = bf2f((u16)(v & 0xffff)), b = bf2f((u16)(v >> 16));
  float ss = a * a + b * b;
#pragma unroll
  for (int off = 32; off; off >>= 1) ss += __shfl_xor(ss, off);
  float norm = sqrtf(ss * (1.0f / 128.0f));
  norm = fmaxf(norm, 1e-12f);
  float inv = 1.0f / norm;
  u32 uv = ((const u32*)(Ub + base))[u];
  float ua = bf2f((u16)(uv & 0xffff)), ub = bf2f((u16)(uv >> 16));
  u32 o = (u32)f2bf(a * inv * ua) | ((u32)f2bf(b * inv * ub) << 16);
  ((u32*)(Ob + base))[u] = o;
}

extern "C" void kernel_launch(void* const* d_in, const int* in_sizes, int n_in,
                              void* d_out, int out_size, void* d_ws, size_t ws_size,
                              hipStream_t stream) {
  (void)in_sizes; (void)n_in; (void)out_size; (void)ws_size;
  const float* x  = (const float*)d_in[0];
  const float* wq = (const float*)d_in[1];
  const float* wk = (const float*)d_in[2];
  const float* wv = (const float*)d_in[3];
  const float* wu = (const float*)d_in[4];
  const float* wo = (const float*)d_in[5];

  char* ws = (char*)d_ws;
  u16* wb   = (u16*)(ws + 0);             // 8 MiB, reused for each weight
  u16* xb   = (u16*)(ws + 8388608);       // 64 MiB (reused as Ob later)
  u16* Qb   = (u16*)(ws + 75497472);      // 64 MiB
  u16* Ub   = (u16*)(ws + 142606336);     // 64 MiB
  float* KVp = (float*)(ws + 209715200);  // 16 MiB: 4x64x128x128 fp32
  u16* KVT  = (u16*)(ws + 226492416);     // 2 MiB (end: 228,589,568 B)
  u16* Ob   = xb;                         // alias: xb dead after projections
  u16* KT   = (u16*)d_out;                // d_out scratch (first 64 MiB)
  u16* VT   = (u16*)d_out + 33554432;     // d_out scratch (second 64 MiB)
  u16* Oraw = (u16*)d_out;                // KT region, dead after KV stage

  // x -> bf16
  cvt_f32_bf16<<<4096, 256, 0, stream>>>((const float4*)x, xb, 8388608);

  // Q
  cvt_f32_bf16<<<4096, 256, 0, stream>>>((const float4*)wq, wb, 1048576);
  gemm256<0><<<512, 512, 0, stream>>>(xb, wb, Qb);
  // K -> KT
  cvt_f32_bf16<<<4096, 256, 0, stream>>>((const float4*)wk, wb, 1048576);
  gemm256<1><<<512, 512, 0, stream>>>(xb, wb, KT);
  // V -> VT
  cvt_f32_bf16<<<4096, 256, 0, stream>>>((const float4*)wv, wb, 1048576);
  gemm256<2><<<512, 512, 0, stream>>>(xb, wb, VT);
  // U
  cvt_f32_bf16<<<4096, 256, 0, stream>>>((const float4*)wu, wb, 1048576);
  gemm256<3><<<512, 512, 0, stream>>>(xb, wb, Ub);

  // KVT[bh][e][d] = sum_l VT[e][l] * KT[d][l]
  gemm128<4><<<dim3(4, 64), 256, 0, stream>>>(VT, KT, KVp);
  kv_reduce<<<4096, 256, 0, stream>>>(KVp, KVT);

  // Oraw = Q @ KVT^T (per head) -> d_out KT region
  gemm128<5><<<dim3(32, 64), 256, 0, stream>>>(Qb, KVT, Oraw);

  // SRMS norm * U -> Ob (= xb)
  srms_mul<<<65536, 256, 0, stream>>>(Oraw, Ub, Ob);

  // out = Ob @ wo^T (fp32, full overwrite of d_out)
  cvt_f32_bf16<<<4096, 256, 0, stream>>>((const float4*)wo, wb, 1048576);
  gemm256<6><<<512, 512, 0, stream>>>(Ob, wb, (float*)d_out);
}